// Round 3
// baseline (2107.724 us; speedup 1.0000x reference)
//
#include <hip/hip_runtime.h>
#include <math.h>

#define NN 50000
#define DD 128
#define ET_N 640000
#define EH_N 320000
#define NL 3

static inline int cdiv(int a, int b){ return (a+b-1)/b; }

// ---------------- compiled-in device scratch (no d_ws dependency) ----------------
__device__ float g_te[(size_t)ET_N*4];
__device__ float g_he[(size_t)EH_N*4];
__device__ int   g_cnt[NN];
__device__ int   g_cur[NN];
__device__ int   g_rs_t[NN+1];
__device__ int   g_rs_h[NN+1];
__device__ int   g_perm_t[ET_N];
__device__ int   g_perm_h[EH_N];
__device__ float g_h [(size_t)NN*DD];
__device__ float g_Q [(size_t)NN*DD];
__device__ float g_K [(size_t)NN*DD];
__device__ float g_V [(size_t)NN*DD];
__device__ float g_S [(size_t)NN*DD];
__device__ float g_tout[(size_t)NN*DD];

// ---------------- tiny helpers ----------------
__global__ void k_zero_cnt(){
  int i = blockIdx.x*256 + threadIdx.x;
  if (i < NN) g_cnt[i] = 0;
}

__global__ void k_copy_h(const float* __restrict__ x){
  int i = blockIdx.x*256 + threadIdx.x;           // float4 index
  if (i < NN*DD/4)
    reinterpret_cast<float4*>(g_h)[i] = reinterpret_cast<const float4*>(x)[i];
}

// ---------- edge embeddings ----------
__global__ void k_edge_emb(const float* __restrict__ attrT, const float* __restrict__ Wt, const float* __restrict__ bt4,
                           const float* __restrict__ attrH, const float* __restrict__ Wh, const float* __restrict__ bh4){
  int e = blockIdx.x*256 + threadIdx.x;
  if (e < ET_N) {
    float a = attrT[e];
#pragma unroll
    for (int j=0;j<4;++j) g_te[(size_t)e*4+j] = a*Wt[j] + bt4[j];
  }
  if (e < EH_N) {
    float a0=attrH[e*3+0], a1=attrH[e*3+1], a2=attrH[e*3+2];
#pragma unroll
    for (int j=0;j<4;++j) g_he[(size_t)e*4+j] = a0*Wh[j]+a1*Wh[4+j]+a2*Wh[8+j]+bh4[j];
  }
}

// ---------- CSR build (by destination) ----------
__global__ void k_hist(const int* __restrict__ dst, int E){
  int e = blockIdx.x*256+threadIdx.x;
  if (e<E) atomicAdd(&g_cnt[dst[e]], 1);
}

__global__ __launch_bounds__(1024) void k_scan(int which){
  int* row_start = which ? g_rs_h : g_rs_t;
  __shared__ int buf[1024];
  int tid = threadIdx.x;
  const int n = NN;
  int chunk = (n + 1023) >> 10;
  int start = tid*chunk; if (start>n) start=n;
  int end = start+chunk; if (end>n) end=n;
  int lsum=0;
  for (int i=start;i<end;++i) lsum += g_cnt[i];
  buf[tid]=lsum;
  __syncthreads();
  for (int off=1; off<1024; off<<=1){
    int t = (tid>=off)? buf[tid-off]:0;
    __syncthreads();
    buf[tid] += t;
    __syncthreads();
  }
  int run = buf[tid]-lsum;     // exclusive prefix of this thread's chunk
  for (int i=start;i<end;++i){ row_start[i]=run; g_cur[i]=run; run += g_cnt[i]; }
  if (tid==1023) row_start[n]=run;
}

__global__ void k_scatter(const int* __restrict__ dst, int which, int E){
  int* perm = which ? g_perm_h : g_perm_t;
  int e = blockIdx.x*256+threadIdx.x;
  if (e<E){ int p = atomicAdd(&g_cur[dst[e]],1); perm[p]=e; }
}

// ---------- f32 GEMM: {Q,K,V,S} = g_h @ W{q,k,v,s} + b ; set via blockIdx.y ----------
struct GemmW { const float* W[4]; const float* b[4]; };

__global__ __launch_bounds__(256) void k_gemm(GemmW gs){
  __shared__ float Asub[32][64];     // [k][row]
  __shared__ float Wsub[32][128];    // [k][col]
  float* const outs[4] = {g_Q, g_K, g_V, g_S};
  const float* __restrict__ W    = gs.W[blockIdx.y];
  const float* __restrict__ bias = gs.b[blockIdx.y];
  float* __restrict__ out        = outs[blockIdx.y];
  const int n = NN;
  int tid = threadIdx.x;
  int tx = tid & 15, ty = tid >> 4;        // rows m0+ty*4..+3, cols tx*8..+7
  int m0 = blockIdx.x*64;
  float acc[4][8];
#pragma unroll
  for (int i=0;i<4;++i)
#pragma unroll
    for (int j=0;j<8;++j) acc[i][j]=0.f;

  for (int kk=0;kk<DD;kk+=32){
#pragma unroll
    for (int li=0;li<2;++li){
      int lin = tid + li*256;              // 0..511 -> 64 rows x 8 float4
      int ar = lin >> 3, ac4 = lin & 7;
      int grow = m0 + ar;
      float4 v = make_float4(0.f,0.f,0.f,0.f);
      if (grow < n) v = *reinterpret_cast<const float4*>(&g_h[(size_t)grow*DD + kk + ac4*4]);
      Asub[ac4*4+0][ar]=v.x; Asub[ac4*4+1][ar]=v.y; Asub[ac4*4+2][ar]=v.z; Asub[ac4*4+3][ar]=v.w;
    }
#pragma unroll
    for (int li=0;li<4;++li){
      int lin = tid + li*256;              // 0..1023 -> 32 rows x 32 float4
      int wr = lin >> 5, wc4 = lin & 31;
      *reinterpret_cast<float4*>(&Wsub[wr][wc4*4]) =
          *reinterpret_cast<const float4*>(&W[(size_t)(kk+wr)*DD + wc4*4]);
    }
    __syncthreads();
#pragma unroll
    for (int k=0;k<32;++k){
      float4 av = *reinterpret_cast<const float4*>(&Asub[k][ty*4]);
      float4 w0 = *reinterpret_cast<const float4*>(&Wsub[k][tx*8]);
      float4 w1 = *reinterpret_cast<const float4*>(&Wsub[k][tx*8+4]);
      float aa[4] = {av.x,av.y,av.z,av.w};
      float ww[8] = {w0.x,w0.y,w0.z,w0.w,w1.x,w1.y,w1.z,w1.w};
#pragma unroll
      for (int i=0;i<4;++i)
#pragma unroll
        for (int j=0;j<8;++j) acc[i][j] += aa[i]*ww[j];
    }
    __syncthreads();
  }
#pragma unroll
  for (int i=0;i<4;++i){
    int grow = m0 + ty*4 + i;
    if (grow < n){
      float4 r0, r1;
      r0.x=acc[i][0]+bias[tx*8+0]; r0.y=acc[i][1]+bias[tx*8+1];
      r0.z=acc[i][2]+bias[tx*8+2]; r0.w=acc[i][3]+bias[tx*8+3];
      r1.x=acc[i][4]+bias[tx*8+4]; r1.y=acc[i][5]+bias[tx*8+5];
      r1.z=acc[i][6]+bias[tx*8+6]; r1.w=acc[i][7]+bias[tx*8+7];
      *reinterpret_cast<float4*>(&out[(size_t)grow*DD + tx*8])   = r0;
      *reinterpret_cast<float4*>(&out[(size_t)grow*DD + tx*8+4]) = r1;
    }
  }
}

// ---------- per-dst-node attention aggregation with online softmax ----------
// block = 128 threads (one per channel), one block per dst node.
// accum==0: g_tout = result; accum==1: g_tout += result
__global__ __launch_bounds__(128) void k_agg(const int* __restrict__ src, int which,
                                             const float* __restrict__ We, int accum){
  const int*   perm = which ? g_perm_h : g_perm_t;
  const int*   rs   = which ? g_rs_h   : g_rs_t;
  const float* eemb = which ? g_he     : g_te;
  int i = blockIdx.x;
  int d = threadIdx.x;
  float w0=We[d], w1=We[DD+d], w2=We[2*DD+d], w3=We[3*DD+d];
  float qd = g_Q[(size_t)i*DD+d];
  float m=-INFINITY, den=0.f, acc=0.f;
  int beg=rs[i], end=rs[i+1];
  for (int idx=beg; idx<end; ++idx){
    int e = perm[idx];
    int s = src[e];
    float e0=eemb[(size_t)e*4+0], e1=eemb[(size_t)e*4+1], e2=eemb[(size_t)e*4+2], e3=eemb[(size_t)e*4+3];
    float ee = e0*w0+e1*w1+e2*w2+e3*w3;
    float kj = g_K[(size_t)s*DD+d] + ee;
    float p = qd*kj;
    // sum over the 32 channels of this head (lanes grouped by 32 inside the wave)
    p += __shfl_xor(p,16); p += __shfl_xor(p,8); p += __shfl_xor(p,4);
    p += __shfl_xor(p,2);  p += __shfl_xor(p,1);
    float a = p*0.17677669529663687f;   // 1/sqrt(32)
    float nm = fmaxf(m,a);
    float sc = expf(m-nm);              // exp(-inf)=0 on first edge
    float ea = expf(a-nm);
    den = den*sc + ea;
    acc = acc*sc + ea*(g_V[(size_t)s*DD+d] + ee);
    m = nm;
  }
  float r = acc/(den+1e-16f) + g_S[(size_t)i*DD+d];
  size_t o = (size_t)i*DD+d;
  if (accum) g_tout[o] += r; else g_tout[o] = r;
}

// ---------- wave(64)-wide helpers ----------
__device__ inline float waveRed(float v){
  v += __shfl_xor(v,32); v += __shfl_xor(v,16); v += __shfl_xor(v,8);
  v += __shfl_xor(v,4);  v += __shfl_xor(v,2);  v += __shfl_xor(v,1);
  return v;
}

// g_h += silu(layernorm(g_tout)) ; one wave per node, 4 nodes per block
__global__ __launch_bounds__(256) void k_combine(const float* __restrict__ g, const float* __restrict__ bt){
  int lane = threadIdx.x & 63;
  int node = blockIdx.x*4 + (threadIdx.x>>6);
  if (node>=NN) return;
  size_t i0 = (size_t)node*DD + lane, i1 = i0+64;
  float v0 = g_tout[i0];
  float v1 = g_tout[i1];
  float s = waveRed(v0+v1);
  float mean = s*(1.f/128.f);
  float d0=v0-mean, d1=v1-mean;
  float q = waveRed(d0*d0+d1*d1);
  float inv = 1.f/sqrtf(q*(1.f/128.f)+1e-5f);
  float c0 = d0*inv*g[lane]+bt[lane];
  float c1 = d1*inv*g[lane+64]+bt[lane+64];
  g_h[i0] += c0/(1.f+expf(-c0));
  g_h[i1] += c1/(1.f+expf(-c1));
}

// in-place final layernorm on g_h
__global__ __launch_bounds__(256) void k_finalln(const float* __restrict__ g, const float* __restrict__ b){
  int lane = threadIdx.x & 63;
  int node = blockIdx.x*4 + (threadIdx.x>>6);
  if (node>=NN) return;
  size_t i0 = (size_t)node*DD + lane, i1 = i0+64;
  float v0 = g_h[i0], v1 = g_h[i1];
  float s = waveRed(v0+v1);
  float mean = s*(1.f/128.f);
  float d0=v0-mean, d1=v1-mean;
  float q = waveRed(d0*d0+d1*d1);
  float inv = 1.f/sqrtf(q*(1.f/128.f)+1e-5f);
  g_h[i0]=d0*inv*g[lane]+b[lane];
  g_h[i1]=d1*inv*g[lane+64]+b[lane+64];
}

// mlp head: out3 = LN(silu(g_h@W1+b1)) @ W2 + b2 ; 8 nodes per block
__global__ __launch_bounds__(128) void k_head(
      const float* __restrict__ W1, const float* __restrict__ b1,
      const float* __restrict__ g, const float* __restrict__ bt,
      const float* __restrict__ W2, const float* __restrict__ b2,
      float* __restrict__ out){
  int d = threadIdx.x;
  int wv = d >> 6;
  int i0 = blockIdx.x*8;
  const int n = NN;
  __shared__ float rows[8][DD];
  __shared__ float comb[2];
#pragma unroll
  for (int t=0;t<8;++t){
    int node = i0+t;
    rows[t][d] = (node<n)? g_h[(size_t)node*DD+d] : 0.f;
  }
  __syncthreads();
  float z[8];
  float b1d = b1[d];
#pragma unroll
  for (int t=0;t<8;++t) z[t]=b1d;
  for (int k=0;k<DD;++k){
    float w = W1[k*DD+d];
#pragma unroll
    for (int t=0;t<8;++t) z[t] += rows[t][k]*w;
  }
#pragma unroll
  for (int t=0;t<8;++t){ float v=z[t]; z[t] = v/(1.f+expf(-v)); }
  float gd=g[d], btd=bt[d];
  float w2a=W2[d*3+0], w2b=W2[d*3+1], w2c=W2[d*3+2];
  float b2a=b2[0], b2b=b2[1], b2c=b2[2];
  for (int t=0;t<8;++t){
    int node=i0+t;
    float zz=z[t];
    float s = waveRed(zz);
    if ((d&63)==0) comb[wv]=s;
    __syncthreads();
    float mean=(comb[0]+comb[1])*(1.f/128.f);
    __syncthreads();
    float dv=zz-mean;
    float q2 = waveRed(dv*dv);
    if ((d&63)==0) comb[wv]=q2;
    __syncthreads();
    float inv = 1.f/sqrtf((comb[0]+comb[1])*(1.f/128.f)+1e-5f);
    __syncthreads();
    float zn = dv*inv*gd+btd;
    float p0 = waveRed(zn*w2a);
    if ((d&63)==0) comb[wv]=p0;
    __syncthreads();
    float o0 = comb[0]+comb[1]+b2a;
    __syncthreads();
    float p1 = waveRed(zn*w2b);
    if ((d&63)==0) comb[wv]=p1;
    __syncthreads();
    float o1 = comb[0]+comb[1]+b2b;
    __syncthreads();
    float p2 = waveRed(zn*w2c);
    if ((d&63)==0) comb[wv]=p2;
    __syncthreads();
    float o2 = comb[0]+comb[1]+b2c;
    __syncthreads();
    if (d==0 && node<n){
      out[(size_t)node*3+0]=o0; out[(size_t)node*3+1]=o1; out[(size_t)node*3+2]=o2;
    }
  }
}

extern "C" void kernel_launch(void* const* d_in, const int* in_sizes, int n_in,
                              void* d_out, int out_size, void* d_ws, size_t ws_size,
                              hipStream_t stream){
  (void)in_sizes; (void)n_in; (void)out_size; (void)d_ws; (void)ws_size;
  const float* x    = (const float*)d_in[0];
  const int*   eit  = (const int*)d_in[1];
  const int*   eih  = (const int*)d_in[2];
  const float* eat  = (const float*)d_in[3];
  const float* eah  = (const float*)d_in[4];
  const float* W_te = (const float*)d_in[5];
  const float* b_te = (const float*)d_in[6];
  const float* W_he = (const float*)d_in[7];
  const float* b_he = (const float*)d_in[8];
  const float *Wq_t=(const float*)d_in[9],  *bq_t=(const float*)d_in[10];
  const float *Wk_t=(const float*)d_in[11], *bk_t=(const float*)d_in[12];
  const float *Wv_t=(const float*)d_in[13], *bv_t=(const float*)d_in[14];
  const float *We_t=(const float*)d_in[15];
  const float *Ws_t=(const float*)d_in[16], *bs_t=(const float*)d_in[17];
  const float *Wq_h=(const float*)d_in[18], *bq_h=(const float*)d_in[19];
  const float *Wk_h=(const float*)d_in[20], *bk_h=(const float*)d_in[21];
  const float *Wv_h=(const float*)d_in[22], *bv_h=(const float*)d_in[23];
  const float *We_h=(const float*)d_in[24];
  const float *Ws_h=(const float*)d_in[25], *bs_h=(const float*)d_in[26];
  const float *norm_g=(const float*)d_in[27], *norm_b=(const float*)d_in[28];
  const float *fg=(const float*)d_in[29], *fb=(const float*)d_in[30];
  const float *dW1=(const float*)d_in[31], *db1=(const float*)d_in[32];
  const float *dg=(const float*)d_in[33],  *dbt=(const float*)d_in[34];
  const float *dW2=(const float*)d_in[35], *db2=(const float*)d_in[36];
  const float *sW1=(const float*)d_in[37], *sb1=(const float*)d_in[38];
  const float *sg=(const float*)d_in[39],  *sbt=(const float*)d_in[40];
  const float *sW2=(const float*)d_in[41], *sb2=(const float*)d_in[42];
  float* outp = (float*)d_out;

  k_copy_h<<<cdiv(NN*DD/4,256),256,0,stream>>>(x);
  k_edge_emb<<<cdiv(ET_N,256),256,0,stream>>>(eat, W_te, b_te, eah, W_he, b_he);

  // CSR temporal (dst = second row of edge_index)
  k_zero_cnt<<<cdiv(NN,256),256,0,stream>>>();
  k_hist<<<cdiv(ET_N,256),256,0,stream>>>(eit+ET_N, ET_N);
  k_scan<<<1,1024,0,stream>>>(0);
  k_scatter<<<cdiv(ET_N,256),256,0,stream>>>(eit+ET_N, 0, ET_N);
  // CSR host
  k_zero_cnt<<<cdiv(NN,256),256,0,stream>>>();
  k_hist<<<cdiv(EH_N,256),256,0,stream>>>(eih+EH_N, EH_N);
  k_scan<<<1,1024,0,stream>>>(1);
  k_scatter<<<cdiv(EH_N,256),256,0,stream>>>(eih+EH_N, 1, EH_N);

  dim3 ggrid(cdiv(NN,64), 4);
  for (int l=0;l<NL;++l){
    GemmW gt;
    gt.W[0]=Wq_t+(size_t)l*DD*DD; gt.b[0]=bq_t+l*DD;
    gt.W[1]=Wk_t+(size_t)l*DD*DD; gt.b[1]=bk_t+l*DD;
    gt.W[2]=Wv_t+(size_t)l*DD*DD; gt.b[2]=bv_t+l*DD;
    gt.W[3]=Ws_t+(size_t)l*DD*DD; gt.b[3]=bs_t+l*DD;
    k_gemm<<<ggrid,256,0,stream>>>(gt);
    k_agg<<<NN,128,0,stream>>>(eit, 0, We_t+(size_t)l*4*DD, 0);

    GemmW gh;
    gh.W[0]=Wq_h+(size_t)l*DD*DD; gh.b[0]=bq_h+l*DD;
    gh.W[1]=Wk_h+(size_t)l*DD*DD; gh.b[1]=bk_h+l*DD;
    gh.W[2]=Wv_h+(size_t)l*DD*DD; gh.b[2]=bv_h+l*DD;
    gh.W[3]=Ws_h+(size_t)l*DD*DD; gh.b[3]=bs_h+l*DD;
    k_gemm<<<ggrid,256,0,stream>>>(gh);
    k_agg<<<NN,128,0,stream>>>(eih, 1, We_h+(size_t)l*4*DD, 1);

    k_combine<<<cdiv(NN,4),256,0,stream>>>(norm_g+(size_t)l*DD, norm_b+(size_t)l*DD);
  }
  k_finalln<<<cdiv(NN,4),256,0,stream>>>(fg, fb);
  k_head<<<cdiv(NN,8),128,0,stream>>>(dW1, db1, dg, dbt, dW2, db2, outp);
  k_head<<<cdiv(NN,8),128,0,stream>>>(sW1, sb1, sg, sbt, sW2, sb2, outp+(size_t)NN*3);
}

// Round 4
// 1678.404 us; speedup vs baseline: 1.2558x; 1.2558x over previous
//
#include <hip/hip_runtime.h>
#include <math.h>

#define NN 50000
#define DD 128
#define ET_N 640000
#define EH_N 320000
#define NL 3

static inline int cdiv(int a, int b){ return (a+b-1)/b; }

// ---------------- compiled-in device scratch (no d_ws dependency) ----------------
__device__ float   g_h [(size_t)NN*DD];
__device__ float   g_Q [2][(size_t)NN*DD];
__device__ float   g_S [2][(size_t)NN*DD];
__device__ ushort2 g_KV[2][(size_t)NN*DD];   // .x = K bf16 bits, .y = V bf16 bits
__device__ float   g_to[(size_t)NN*DD];      // temporal conv output
__device__ float   g_ho[(size_t)NN*DD];      // host conv output
__device__ int     g_cnt[2][NN];
__device__ int     g_cur[2][NN];
__device__ int     g_rs [2][NN+1];
__device__ int     g_srcc[2][ET_N];          // CSR-ordered src (conv1 uses first EH_N)
__device__ float4  g_ee  [2][ET_N];          // CSR-ordered 4-d edge embedding

__device__ inline unsigned short f2bf(float f){
  unsigned u = __float_as_uint(f);
  unsigned r = (u + 0x7fffu + ((u>>16)&1u)) >> 16;   // RNE
  return (unsigned short)r;
}
__device__ inline float bf2f(unsigned short s){
  return __uint_as_float(((unsigned)s)<<16);
}

// ---------------- tiny helpers ----------------
__global__ void k_copy_h(const float* __restrict__ x){
  int i = blockIdx.x*256 + threadIdx.x;           // float4 index
  if (i < NN*DD/4)
    reinterpret_cast<float4*>(g_h)[i] = reinterpret_cast<const float4*>(x)[i];
}

__global__ void k_zero_cnt(){
  int i = blockIdx.x*256 + threadIdx.x;
  if (i < NN) g_cnt[blockIdx.y][i] = 0;
}

// ---------- CSR build (by destination) ----------
__global__ void k_hist(const int* __restrict__ dstT, const int* __restrict__ dstH){
  int which = blockIdx.y;
  int E = which ? EH_N : ET_N;
  const int* dst = which ? dstH : dstT;
  int e = blockIdx.x*256+threadIdx.x;
  if (e<E) atomicAdd(&g_cnt[which][dst[e]], 1);
}

__global__ __launch_bounds__(1024) void k_scan(){
  int which = blockIdx.y;
  int* row_start = g_rs[which];
  const int* cnt = g_cnt[which];
  int* cur = g_cur[which];
  __shared__ int buf[1024];
  int tid = threadIdx.x;
  const int n = NN;
  int chunk = (n + 1023) >> 10;
  int start = tid*chunk; if (start>n) start=n;
  int end = start+chunk; if (end>n) end=n;
  int lsum=0;
  for (int i=start;i<end;++i) lsum += cnt[i];
  buf[tid]=lsum;
  __syncthreads();
  for (int off=1; off<1024; off<<=1){
    int t = (tid>=off)? buf[tid-off]:0;
    __syncthreads();
    buf[tid] += t;
    __syncthreads();
  }
  int run = buf[tid]-lsum;     // exclusive prefix of this thread's chunk
  for (int i=start;i<end;++i){ row_start[i]=run; cur[i]=run; run += cnt[i]; }
  if (tid==1023) row_start[n]=run;
}

// scatter + fused edge-encoder: writes CSR-ordered src and 4-d edge embedding
__global__ void k_scatter(const int* __restrict__ eit, const int* __restrict__ eih,
                          const float* __restrict__ attrT, const float* __restrict__ attrH,
                          const float* __restrict__ Wt, const float* __restrict__ bt4,
                          const float* __restrict__ Wh, const float* __restrict__ bh4){
  int which = blockIdx.y;
  int e = blockIdx.x*256+threadIdx.x;
  if (which==0){
    if (e>=ET_N) return;
    int src = eit[e], dst = eit[ET_N+e];
    int p = atomicAdd(&g_cur[0][dst],1);
    g_srcc[0][p]=src;
    float a = attrT[e];
    g_ee[0][p] = make_float4(a*Wt[0]+bt4[0], a*Wt[1]+bt4[1], a*Wt[2]+bt4[2], a*Wt[3]+bt4[3]);
  } else {
    if (e>=EH_N) return;
    int src = eih[e], dst = eih[EH_N+e];
    int p = atomicAdd(&g_cur[1][dst],1);
    g_srcc[1][p]=src;
    float a0=attrH[e*3+0], a1=attrH[e*3+1], a2=attrH[e*3+2];
    float4 v;
    v.x = a0*Wh[0]+a1*Wh[4]+a2*Wh[8]+bh4[0];
    v.y = a0*Wh[1]+a1*Wh[5]+a2*Wh[9]+bh4[1];
    v.z = a0*Wh[2]+a1*Wh[6]+a2*Wh[10]+bh4[2];
    v.w = a0*Wh[3]+a1*Wh[7]+a2*Wh[11]+bh4[3];
    g_ee[1][p] = v;
  }
}

// ---------- f32 GEMM: 8 weight sets (t:QKVS, h:QKVS) via blockIdx.y ----------
struct GemmW { const float* W[8]; const float* b[8]; };

__global__ __launch_bounds__(256) void k_gemm(GemmW gs){
  __shared__ float Asub[32][64];     // [k][row]
  __shared__ float Wsub[32][128];    // [k][col]
  int set = blockIdx.y;
  int conv = set >> 2;               // 0 temporal, 1 host
  int kind = set & 3;                // 0 Q, 1 K, 2 V, 3 S
  const float* __restrict__ W    = gs.W[set];
  const float* __restrict__ bias = gs.b[set];
  const int n = NN;
  int tid = threadIdx.x;
  int tx = tid & 15, ty = tid >> 4;  // rows m0+ty*4..+3, cols tx*8..+7
  int m0 = blockIdx.x*64;
  float acc[4][8];
#pragma unroll
  for (int i=0;i<4;++i)
#pragma unroll
    for (int j=0;j<8;++j) acc[i][j]=0.f;

  for (int kk=0;kk<DD;kk+=32){
#pragma unroll
    for (int li=0;li<2;++li){
      int lin = tid + li*256;        // 0..511 -> 64 rows x 8 float4
      int ar = lin >> 3, ac4 = lin & 7;
      int grow = m0 + ar;
      float4 v = make_float4(0.f,0.f,0.f,0.f);
      if (grow < n) v = *reinterpret_cast<const float4*>(&g_h[(size_t)grow*DD + kk + ac4*4]);
      Asub[ac4*4+0][ar]=v.x; Asub[ac4*4+1][ar]=v.y; Asub[ac4*4+2][ar]=v.z; Asub[ac4*4+3][ar]=v.w;
    }
#pragma unroll
    for (int li=0;li<4;++li){
      int lin = tid + li*256;        // 0..1023 -> 32 rows x 32 float4
      int wr = lin >> 5, wc4 = lin & 31;
      *reinterpret_cast<float4*>(&Wsub[wr][wc4*4]) =
          *reinterpret_cast<const float4*>(&W[(size_t)(kk+wr)*DD + wc4*4]);
    }
    __syncthreads();
#pragma unroll
    for (int k=0;k<32;++k){
      float4 av = *reinterpret_cast<const float4*>(&Asub[k][ty*4]);
      float4 w0 = *reinterpret_cast<const float4*>(&Wsub[k][tx*8]);
      float4 w1 = *reinterpret_cast<const float4*>(&Wsub[k][tx*8+4]);
      float aa[4] = {av.x,av.y,av.z,av.w};
      float ww[8] = {w0.x,w0.y,w0.z,w0.w,w1.x,w1.y,w1.z,w1.w};
#pragma unroll
      for (int i=0;i<4;++i)
#pragma unroll
        for (int j=0;j<8;++j) acc[i][j] += aa[i]*ww[j];
    }
    __syncthreads();
  }
#pragma unroll
  for (int i=0;i<4;++i){
    int grow = m0 + ty*4 + i;
    if (grow >= n) continue;
    size_t base = (size_t)grow*DD + tx*8;
    if (kind==0 || kind==3){
      float* o = (kind==0) ? g_Q[conv] : g_S[conv];
      float4 r0, r1;
      r0.x=acc[i][0]+bias[tx*8+0]; r0.y=acc[i][1]+bias[tx*8+1];
      r0.z=acc[i][2]+bias[tx*8+2]; r0.w=acc[i][3]+bias[tx*8+3];
      r1.x=acc[i][4]+bias[tx*8+4]; r1.y=acc[i][5]+bias[tx*8+5];
      r1.z=acc[i][6]+bias[tx*8+6]; r1.w=acc[i][7]+bias[tx*8+7];
      *reinterpret_cast<float4*>(&o[base])   = r0;
      *reinterpret_cast<float4*>(&o[base+4]) = r1;
    } else {
      ushort2* kvp = g_KV[conv];
#pragma unroll
      for (int j=0;j<8;++j){
        unsigned short bv = f2bf(acc[i][j]+bias[tx*8+j]);
        if (kind==1) kvp[base+j].x = bv; else kvp[base+j].y = bv;
      }
    }
  }
}

// ---------- per-dst-node attention aggregation with online softmax ----------
// grid (NN, 2); block = 128 threads (one per channel); conv = blockIdx.y
__global__ __launch_bounds__(128) void k_agg(const float* __restrict__ WeT,
                                             const float* __restrict__ WeH){
  int conv = blockIdx.y;
  int i = blockIdx.x;
  int d = threadIdx.x;
  const float* We = conv ? WeH : WeT;
  float w0=We[d], w1=We[DD+d], w2=We[2*DD+d], w3=We[3*DD+d];
  float qd = g_Q[conv][(size_t)i*DD+d];
  const int*     srcc = g_srcc[conv];
  const float4*  ee   = g_ee[conv];
  const ushort2* KV   = g_KV[conv];
  int beg=g_rs[conv][i], end=g_rs[conv][i+1];
  float m=-INFINITY, den=0.f, acc=0.f;
  if (beg<end){
    // one-deep software pipeline on the src -> KV gather chain
    int s = srcc[beg];
    float4 e4 = ee[beg];
    ushort2 kv = KV[(size_t)s*DD+d];
    for (int idx=beg; idx<end; ++idx){
      ushort2 kv_n = kv; float4 e4_n = e4;
      if (idx+1<end){
        int s_n = srcc[idx+1];
        e4_n = ee[idx+1];
        kv_n = KV[(size_t)s_n*DD+d];
      }
      float eev = e4.x*w0 + e4.y*w1 + e4.z*w2 + e4.w*w3;
      float kf = bf2f(kv.x), vf = bf2f(kv.y);
      float p = qd*(kf+eev);
      p += __shfl_xor(p,16); p += __shfl_xor(p,8); p += __shfl_xor(p,4);
      p += __shfl_xor(p,2);  p += __shfl_xor(p,1);
      float a = p*0.17677669529663687f;   // 1/sqrt(32)
      float nm = fmaxf(m,a);
      float sc = __expf(m-nm);            // exp(-inf)=0 on first edge
      float ea = __expf(a-nm);
      den = den*sc + ea;
      acc = acc*sc + ea*(vf+eev);
      m = nm;
      kv = kv_n; e4 = e4_n;
    }
  }
  float r = acc/(den+1e-16f) + g_S[conv][(size_t)i*DD+d];
  float* o = conv ? g_ho : g_to;
  o[(size_t)i*DD+d] = r;
}

// ---------- wave(64)-wide helpers ----------
__device__ inline float waveRed(float v){
  v += __shfl_xor(v,32); v += __shfl_xor(v,16); v += __shfl_xor(v,8);
  v += __shfl_xor(v,4);  v += __shfl_xor(v,2);  v += __shfl_xor(v,1);
  return v;
}

// g_h += silu(layernorm(g_to + g_ho)) ; one wave per node, 4 nodes per block
__global__ __launch_bounds__(256) void k_combine(const float* __restrict__ g, const float* __restrict__ bt){
  int lane = threadIdx.x & 63;
  int node = blockIdx.x*4 + (threadIdx.x>>6);
  if (node>=NN) return;
  size_t i0 = (size_t)node*DD + lane, i1 = i0+64;
  float v0 = g_to[i0] + g_ho[i0];
  float v1 = g_to[i1] + g_ho[i1];
  float s = waveRed(v0+v1);
  float mean = s*(1.f/128.f);
  float d0=v0-mean, d1=v1-mean;
  float q = waveRed(d0*d0+d1*d1);
  float inv = 1.f/sqrtf(q*(1.f/128.f)+1e-5f);
  float c0 = d0*inv*g[lane]+bt[lane];
  float c1 = d1*inv*g[lane+64]+bt[lane+64];
  g_h[i0] += c0/(1.f+expf(-c0));
  g_h[i1] += c1/(1.f+expf(-c1));
}

// in-place final layernorm on g_h
__global__ __launch_bounds__(256) void k_finalln(const float* __restrict__ g, const float* __restrict__ b){
  int lane = threadIdx.x & 63;
  int node = blockIdx.x*4 + (threadIdx.x>>6);
  if (node>=NN) return;
  size_t i0 = (size_t)node*DD + lane, i1 = i0+64;
  float v0 = g_h[i0], v1 = g_h[i1];
  float s = waveRed(v0+v1);
  float mean = s*(1.f/128.f);
  float d0=v0-mean, d1=v1-mean;
  float q = waveRed(d0*d0+d1*d1);
  float inv = 1.f/sqrtf(q*(1.f/128.f)+1e-5f);
  g_h[i0]=d0*inv*g[lane]+b[lane];
  g_h[i1]=d1*inv*g[lane+64]+b[lane+64];
}

// mlp head: out3 = LN(silu(g_h@W1+b1)) @ W2 + b2 ; 8 nodes per block
__global__ __launch_bounds__(128) void k_head(
      const float* __restrict__ W1, const float* __restrict__ b1,
      const float* __restrict__ g, const float* __restrict__ bt,
      const float* __restrict__ W2, const float* __restrict__ b2,
      float* __restrict__ out){
  int d = threadIdx.x;
  int wv = d >> 6;
  int i0 = blockIdx.x*8;
  const int n = NN;
  __shared__ float rows[8][DD];
  __shared__ float comb[2];
#pragma unroll
  for (int t=0;t<8;++t){
    int node = i0+t;
    rows[t][d] = (node<n)? g_h[(size_t)node*DD+d] : 0.f;
  }
  __syncthreads();
  float z[8];
  float b1d = b1[d];
#pragma unroll
  for (int t=0;t<8;++t) z[t]=b1d;
  for (int k=0;k<DD;++k){
    float w = W1[k*DD+d];
#pragma unroll
    for (int t=0;t<8;++t) z[t] += rows[t][k]*w;
  }
#pragma unroll
  for (int t=0;t<8;++t){ float v=z[t]; z[t] = v/(1.f+expf(-v)); }
  float gd=g[d], btd=bt[d];
  float w2a=W2[d*3+0], w2b=W2[d*3+1], w2c=W2[d*3+2];
  float b2a=b2[0], b2b=b2[1], b2c=b2[2];
  for (int t=0;t<8;++t){
    int node=i0+t;
    float zz=z[t];
    float s = waveRed(zz);
    if ((d&63)==0) comb[wv]=s;
    __syncthreads();
    float mean=(comb[0]+comb[1])*(1.f/128.f);
    __syncthreads();
    float dv=zz-mean;
    float q2 = waveRed(dv*dv);
    if ((d&63)==0) comb[wv]=q2;
    __syncthreads();
    float inv = 1.f/sqrtf((comb[0]+comb[1])*(1.f/128.f)+1e-5f);
    __syncthreads();
    float zn = dv*inv*gd+btd;
    float p0 = waveRed(zn*w2a);
    if ((d&63)==0) comb[wv]=p0;
    __syncthreads();
    float o0 = comb[0]+comb[1]+b2a;
    __syncthreads();
    float p1 = waveRed(zn*w2b);
    if ((d&63)==0) comb[wv]=p1;
    __syncthreads();
    float o1 = comb[0]+comb[1]+b2b;
    __syncthreads();
    float p2 = waveRed(zn*w2c);
    if ((d&63)==0) comb[wv]=p2;
    __syncthreads();
    float o2 = comb[0]+comb[1]+b2c;
    __syncthreads();
    if (d==0 && node<n){
      out[(size_t)node*3+0]=o0; out[(size_t)node*3+1]=o1; out[(size_t)node*3+2]=o2;
    }
  }
}

extern "C" void kernel_launch(void* const* d_in, const int* in_sizes, int n_in,
                              void* d_out, int out_size, void* d_ws, size_t ws_size,
                              hipStream_t stream){
  (void)in_sizes; (void)n_in; (void)out_size; (void)d_ws; (void)ws_size;
  const float* x    = (const float*)d_in[0];
  const int*   eit  = (const int*)d_in[1];
  const int*   eih  = (const int*)d_in[2];
  const float* eat  = (const float*)d_in[3];
  const float* eah  = (const float*)d_in[4];
  const float* W_te = (const float*)d_in[5];
  const float* b_te = (const float*)d_in[6];
  const float* W_he = (const float*)d_in[7];
  const float* b_he = (const float*)d_in[8];
  const float *Wq_t=(const float*)d_in[9],  *bq_t=(const float*)d_in[10];
  const float *Wk_t=(const float*)d_in[11], *bk_t=(const float*)d_in[12];
  const float *Wv_t=(const float*)d_in[13], *bv_t=(const float*)d_in[14];
  const float *We_t=(const float*)d_in[15];
  const float *Ws_t=(const float*)d_in[16], *bs_t=(const float*)d_in[17];
  const float *Wq_h=(const float*)d_in[18], *bq_h=(const float*)d_in[19];
  const float *Wk_h=(const float*)d_in[20], *bk_h=(const float*)d_in[21];
  const float *Wv_h=(const float*)d_in[22], *bv_h=(const float*)d_in[23];
  const float *We_h=(const float*)d_in[24];
  const float *Ws_h=(const float*)d_in[25], *bs_h=(const float*)d_in[26];
  const float *norm_g=(const float*)d_in[27], *norm_b=(const float*)d_in[28];
  const float *fg=(const float*)d_in[29], *fb=(const float*)d_in[30];
  const float *dW1=(const float*)d_in[31], *db1=(const float*)d_in[32];
  const float *dg=(const float*)d_in[33],  *dbt=(const float*)d_in[34];
  const float *dW2=(const float*)d_in[35], *db2=(const float*)d_in[36];
  const float *sW1=(const float*)d_in[37], *sb1=(const float*)d_in[38];
  const float *sg=(const float*)d_in[39],  *sbt=(const float*)d_in[40];
  const float *sW2=(const float*)d_in[41], *sb2=(const float*)d_in[42];
  float* outp = (float*)d_out;

  k_copy_h<<<cdiv(NN*DD/4,256),256,0,stream>>>(x);
  k_zero_cnt<<<dim3(cdiv(NN,256),2),256,0,stream>>>();
  k_hist<<<dim3(cdiv(ET_N,256),2),256,0,stream>>>(eit+ET_N, eih+EH_N);
  k_scan<<<dim3(1,2),1024,0,stream>>>();
  k_scatter<<<dim3(cdiv(ET_N,256),2),256,0,stream>>>(eit, eih, eat, eah, W_te, b_te, W_he, b_he);

  dim3 ggrid(cdiv(NN,64), 8);
  for (int l=0;l<NL;++l){
    GemmW g8;
    g8.W[0]=Wq_t+(size_t)l*DD*DD; g8.b[0]=bq_t+(size_t)l*DD;
    g8.W[1]=Wk_t+(size_t)l*DD*DD; g8.b[1]=bk_t+(size_t)l*DD;
    g8.W[2]=Wv_t+(size_t)l*DD*DD; g8.b[2]=bv_t+(size_t)l*DD;
    g8.W[3]=Ws_t+(size_t)l*DD*DD; g8.b[3]=bs_t+(size_t)l*DD;
    g8.W[4]=Wq_h+(size_t)l*DD*DD; g8.b[4]=bq_h+(size_t)l*DD;
    g8.W[5]=Wk_h+(size_t)l*DD*DD; g8.b[5]=bk_h+(size_t)l*DD;
    g8.W[6]=Wv_h+(size_t)l*DD*DD; g8.b[6]=bv_h+(size_t)l*DD;
    g8.W[7]=Ws_h+(size_t)l*DD*DD; g8.b[7]=bs_h+(size_t)l*DD;
    k_gemm<<<ggrid,256,0,stream>>>(g8);
    k_agg<<<dim3(NN,2),128,0,stream>>>(We_t+(size_t)l*4*DD, We_h+(size_t)l*4*DD);
    k_combine<<<cdiv(NN,4),256,0,stream>>>(norm_g+(size_t)l*DD, norm_b+(size_t)l*DD);
  }
  k_finalln<<<cdiv(NN,4),256,0,stream>>>(fg, fb);
  k_head<<<cdiv(NN,8),128,0,stream>>>(dW1, db1, dg, dbt, dW2, db2, outp);
  k_head<<<cdiv(NN,8),128,0,stream>>>(sW1, sb1, sg, sbt, sW2, sb2, outp+(size_t)NN*3);
}

// Round 5
// 1384.378 us; speedup vs baseline: 1.5225x; 1.2124x over previous
//
#include <hip/hip_runtime.h>
#include <math.h>

#define NN 50000
#define DD 128
#define ET_N 640000
#define EH_N 320000
#define NL 3

static inline int cdiv(int a, int b){ return (a+b-1)/b; }

typedef __attribute__((ext_vector_type(8))) short short8;
typedef __attribute__((ext_vector_type(4))) float f32x4;

// ---------------- compiled-in device scratch (no d_ws dependency) ----------------
__device__ float   g_h [(size_t)NN*DD];
__device__ unsigned short g_hb[(size_t)NN*DD];        // bf16 copy of h (GEMM A input)
__device__ unsigned short g_Wb[(size_t)NL*8*DD*DD];   // bf16, TRANSPOSED [n][k]; l*8 + {tQ,tK,tV,tS,hQ,hK,hV,hS}
__device__ float   g_Q [2][(size_t)NN*DD];
__device__ float   g_S [2][(size_t)NN*DD];
__device__ ushort2 g_KV[2][(size_t)NN*DD];   // .x = K bf16 bits, .y = V bf16 bits
__device__ float   g_to[(size_t)NN*DD];      // temporal conv output
__device__ float   g_ho[(size_t)NN*DD];      // host conv output
__device__ int     g_cnt[2][NN];
__device__ int     g_cur[2][NN];
__device__ int     g_rs [2][NN+1];
__device__ int     g_srcc[2][ET_N];          // CSR-ordered src (conv1 uses first EH_N)
__device__ float4  g_ee  [2][ET_N];          // CSR-ordered 4-d edge embedding

__device__ inline unsigned short f2bf(float f){
  unsigned u = __float_as_uint(f);
  unsigned r = (u + 0x7fffu + ((u>>16)&1u)) >> 16;   // RNE
  return (unsigned short)r;
}
__device__ inline float bf2f(unsigned short s){
  return __uint_as_float(((unsigned)s)<<16);
}

// ---------------- tiny helpers ----------------
__global__ void k_copy_h(const float* __restrict__ x){
  int i = blockIdx.x*256 + threadIdx.x;           // float4 index
  if (i < NN*DD/4){
    float4 v = reinterpret_cast<const float4*>(x)[i];
    reinterpret_cast<float4*>(g_h)[i] = v;
    ushort4 b; b.x=f2bf(v.x); b.y=f2bf(v.y); b.z=f2bf(v.z); b.w=f2bf(v.w);
    reinterpret_cast<ushort4*>(g_hb)[i] = b;
  }
}

__global__ void k_zero_cnt(){
  int i = blockIdx.x*256 + threadIdx.x;
  if (i < NN) g_cnt[blockIdx.y][i] = 0;
}

// convert + transpose conv weights to bf16 [n][k]
struct WPtrs { const float* W[24]; };
__global__ __launch_bounds__(256) void k_cvtw(WPtrs wp){
  int mat = blockIdx.y;                    // 0..23  (= l*8 + set)
  const float* W = wp.W[mat];
  int e = blockIdx.x*256 + threadIdx.x;    // output index, 0..16383
  int n = e >> 7, k = e & 127;
  g_Wb[(size_t)mat*DD*DD + e] = f2bf(W[k*DD+n]);
}

// ---------- CSR build (by destination) ----------
__global__ void k_hist(const int* __restrict__ dstT, const int* __restrict__ dstH){
  int which = blockIdx.y;
  int E = which ? EH_N : ET_N;
  const int* dst = which ? dstH : dstT;
  int e = blockIdx.x*256+threadIdx.x;
  if (e<E) atomicAdd(&g_cnt[which][dst[e]], 1);
}

__global__ __launch_bounds__(1024) void k_scan(){
  int which = blockIdx.y;
  int* row_start = g_rs[which];
  const int* cnt = g_cnt[which];
  int* cur = g_cur[which];
  __shared__ int buf[1024];
  int tid = threadIdx.x;
  const int n = NN;
  int chunk = (n + 1023) >> 10;
  int start = tid*chunk; if (start>n) start=n;
  int end = start+chunk; if (end>n) end=n;
  int lsum=0;
  for (int i=start;i<end;++i) lsum += cnt[i];
  buf[tid]=lsum;
  __syncthreads();
  for (int off=1; off<1024; off<<=1){
    int t = (tid>=off)? buf[tid-off]:0;
    __syncthreads();
    buf[tid] += t;
    __syncthreads();
  }
  int run = buf[tid]-lsum;
  for (int i=start;i<end;++i){ row_start[i]=run; cur[i]=run; run += cnt[i]; }
  if (tid==1023) row_start[n]=run;
}

// scatter + fused edge-encoder: writes CSR-ordered src and 4-d edge embedding
__global__ void k_scatter(const int* __restrict__ eit, const int* __restrict__ eih,
                          const float* __restrict__ attrT, const float* __restrict__ attrH,
                          const float* __restrict__ Wt, const float* __restrict__ bt4,
                          const float* __restrict__ Wh, const float* __restrict__ bh4){
  int which = blockIdx.y;
  int e = blockIdx.x*256+threadIdx.x;
  if (which==0){
    if (e>=ET_N) return;
    int src = eit[e], dst = eit[ET_N+e];
    int p = atomicAdd(&g_cur[0][dst],1);
    g_srcc[0][p]=src;
    float a = attrT[e];
    g_ee[0][p] = make_float4(a*Wt[0]+bt4[0], a*Wt[1]+bt4[1], a*Wt[2]+bt4[2], a*Wt[3]+bt4[3]);
  } else {
    if (e>=EH_N) return;
    int src = eih[e], dst = eih[EH_N+e];
    int p = atomicAdd(&g_cur[1][dst],1);
    g_srcc[1][p]=src;
    float a0=attrH[e*3+0], a1=attrH[e*3+1], a2=attrH[e*3+2];
    float4 v;
    v.x = a0*Wh[0]+a1*Wh[4]+a2*Wh[8]+bh4[0];
    v.y = a0*Wh[1]+a1*Wh[5]+a2*Wh[9]+bh4[1];
    v.z = a0*Wh[2]+a1*Wh[6]+a2*Wh[10]+bh4[2];
    v.w = a0*Wh[3]+a1*Wh[7]+a2*Wh[11]+bh4[3];
    g_ee[1][p] = v;
  }
}

// ---------- bf16 MFMA GEMM ----------
// grid (cdiv(NN,64), 6): y = conv*3 + kind, kind 0=Q, 1=KV(two matmuls), 2=S
// block 256 = 4 waves; wave w owns cols [w*32, w*32+32); 64x128 tile; K=128 staged once.
// LDS XOR swizzle: off ^= ((row&7)<<4) on 16B-granular offsets (G4 fix for 256B-stride tiles).
struct BiasP { const float* b[8]; };

__global__ __launch_bounds__(256) void k_gemm_mfma(int l, BiasP bp){
  __shared__ unsigned short lA[64*DD];    // 16 KB
  __shared__ unsigned short lB[DD*DD];    // 32 KB
  int y = blockIdx.y;
  int conv = y/3, kind = y%3;             // 0 Q, 1 KV, 2 S
  int setbase = l*8 + conv*4;
  const unsigned short* Wm0 = &g_Wb[(size_t)(setbase + (kind==0?0:(kind==1?1:3)))*DD*DD];
  const unsigned short* Wm1 = &g_Wb[(size_t)(setbase+2)*DD*DD];   // V weights (kind==1 only)
  int tid = threadIdx.x;
  int m0 = blockIdx.x*64;

  // stage A: 64 rows x 16 chunks(16B) = 1024 chunks, 4 passes
#pragma unroll
  for (int p=0;p<4;++p){
    int c = tid + p*256;
    int row = c >> 4, col16 = c & 15;
    int grow = m0 + row;
    uint4 v = make_uint4(0,0,0,0);
    if (grow < NN) v = *reinterpret_cast<const uint4*>(&g_hb[(size_t)grow*DD + col16*8]);
    int off = (row*256 + col16*16) ^ ((row&7)<<4);
    *reinterpret_cast<uint4*>((char*)lA + off) = v;
  }
  // stage B = Wm0: 128 rows x 16 chunks = 2048 chunks, 8 passes
#pragma unroll
  for (int p=0;p<8;++p){
    int c = tid + p*256;
    int row = c >> 4, col16 = c & 15;
    uint4 v = *reinterpret_cast<const uint4*>(&Wm0[(size_t)row*DD + col16*8]);
    int off = (row*256 + col16*16) ^ ((row&7)<<4);
    *reinterpret_cast<uint4*>((char*)lB + off) = v;
  }
  __syncthreads();

  int wave = tid >> 6, lane = tid & 63;
  int lrow = lane & 15, kg = lane >> 4;   // kg = k-group 0..3
  int n0w = wave*32;

  // A fragments for all kk into registers: a[kk][mi]
  short8 a[4][4];
#pragma unroll
  for (int kk=0;kk<4;++kk){
    int kbyte = kk*64 + kg*16;
#pragma unroll
    for (int mi=0;mi<4;++mi){
      int row = mi*16 + lrow;
      int off = (row*256 + kbyte) ^ ((row&7)<<4);
      a[kk][mi] = *reinterpret_cast<const short8*>((char*)lA + off);
    }
  }

  f32x4 acc[4][2];
#pragma unroll
  for (int mi=0;mi<4;++mi)
#pragma unroll
    for (int ni=0;ni<2;++ni) acc[mi][ni] = (f32x4){0.f,0.f,0.f,0.f};

#pragma unroll
  for (int kk=0;kk<4;++kk){
    int kbyte = kk*64 + kg*16;
    short8 b[2];
#pragma unroll
    for (int ni=0;ni<2;++ni){
      int n = n0w + ni*16 + lrow;
      int off = (n*256 + kbyte) ^ ((n&7)<<4);
      b[ni] = *reinterpret_cast<const short8*>((char*)lB + off);
    }
#pragma unroll
    for (int mi=0;mi<4;++mi)
#pragma unroll
      for (int ni=0;ni<2;++ni)
        acc[mi][ni] = __builtin_amdgcn_mfma_f32_16x16x32_bf16(a[kk][mi], b[ni], acc[mi][ni], 0,0,0);
  }

  f32x4 acc2[4][2];
  if (kind==1){
    __syncthreads();       // everyone done reading lB (K weights)
#pragma unroll
    for (int p=0;p<8;++p){
      int c = tid + p*256;
      int row = c >> 4, col16 = c & 15;
      uint4 v = *reinterpret_cast<const uint4*>(&Wm1[(size_t)row*DD + col16*8]);
      int off = (row*256 + col16*16) ^ ((row&7)<<4);
      *reinterpret_cast<uint4*>((char*)lB + off) = v;
    }
    __syncthreads();
#pragma unroll
    for (int mi=0;mi<4;++mi)
#pragma unroll
      for (int ni=0;ni<2;++ni) acc2[mi][ni] = (f32x4){0.f,0.f,0.f,0.f};
#pragma unroll
    for (int kk=0;kk<4;++kk){
      int kbyte = kk*64 + kg*16;
      short8 b[2];
#pragma unroll
      for (int ni=0;ni<2;++ni){
        int n = n0w + ni*16 + lrow;
        int off = (n*256 + kbyte) ^ ((n&7)<<4);
        b[ni] = *reinterpret_cast<const short8*>((char*)lB + off);
      }
#pragma unroll
      for (int mi=0;mi<4;++mi)
#pragma unroll
        for (int ni=0;ni<2;++ni)
          acc2[mi][ni] = __builtin_amdgcn_mfma_f32_16x16x32_bf16(a[kk][mi], b[ni], acc2[mi][ni], 0,0,0);
    }
  }

  // epilogue: C/D layout col=lane&15, row=(lane>>4)*4+reg  [m89]
  const float* bias0 = bp.b[conv*4 + (kind==0?0:(kind==1?1:3))];
  const float* bias1 = bp.b[conv*4 + 2];
#pragma unroll
  for (int ni=0;ni<2;++ni){
    int col = n0w + ni*16 + lrow;
    float bs0 = bias0[col];
    float bs1 = (kind==1) ? bias1[col] : 0.f;
#pragma unroll
    for (int mi=0;mi<4;++mi){
#pragma unroll
      for (int r=0;r<4;++r){
        int row = m0 + mi*16 + kg*4 + r;
        if (row >= NN) continue;
        size_t o = (size_t)row*DD + col;
        if (kind==1){
          ushort2 kv;
          kv.x = f2bf(acc[mi][ni][r]  + bs0);
          kv.y = f2bf(acc2[mi][ni][r] + bs1);
          g_KV[conv][o] = kv;
        } else {
          float* op = (kind==0) ? g_Q[conv] : g_S[conv];
          op[o] = acc[mi][ni][r] + bs0;
        }
      }
    }
  }
}

// ---------- per-dst-node attention aggregation with online softmax ----------
// grid (NN, 2); block = 128 threads (one per channel); conv = blockIdx.y
__global__ __launch_bounds__(128) void k_agg(const float* __restrict__ WeT,
                                             const float* __restrict__ WeH){
  int conv = blockIdx.y;
  int i = blockIdx.x;
  int d = threadIdx.x;
  const float* We = conv ? WeH : WeT;
  float w0=We[d], w1=We[DD+d], w2=We[2*DD+d], w3=We[3*DD+d];
  float qd = g_Q[conv][(size_t)i*DD+d];
  const int*     srcc = g_srcc[conv];
  const float4*  ee   = g_ee[conv];
  const ushort2* KV   = g_KV[conv];
  int beg=g_rs[conv][i], end=g_rs[conv][i+1];
  float m=-INFINITY, den=0.f, acc=0.f;
  if (beg<end){
    int s = srcc[beg];
    float4 e4 = ee[beg];
    ushort2 kv = KV[(size_t)s*DD+d];
    for (int idx=beg; idx<end; ++idx){
      ushort2 kv_n = kv; float4 e4_n = e4;
      if (idx+1<end){
        int s_n = srcc[idx+1];
        e4_n = ee[idx+1];
        kv_n = KV[(size_t)s_n*DD+d];
      }
      float eev = e4.x*w0 + e4.y*w1 + e4.z*w2 + e4.w*w3;
      float kf = bf2f(kv.x), vf = bf2f(kv.y);
      float p = qd*(kf+eev);
      p += __shfl_xor(p,16); p += __shfl_xor(p,8); p += __shfl_xor(p,4);
      p += __shfl_xor(p,2);  p += __shfl_xor(p,1);
      float a = p*0.17677669529663687f;   // 1/sqrt(32)
      float nm = fmaxf(m,a);
      float sc = __expf(m-nm);
      float ea = __expf(a-nm);
      den = den*sc + ea;
      acc = acc*sc + ea*(vf+eev);
      m = nm;
      kv = kv_n; e4 = e4_n;
    }
  }
  float r = acc/(den+1e-16f) + g_S[conv][(size_t)i*DD+d];
  float* o = conv ? g_ho : g_to;
  o[(size_t)i*DD+d] = r;
}

// ---------- wave(64)-wide helpers ----------
__device__ inline float waveRed(float v){
  v += __shfl_xor(v,32); v += __shfl_xor(v,16); v += __shfl_xor(v,8);
  v += __shfl_xor(v,4);  v += __shfl_xor(v,2);  v += __shfl_xor(v,1);
  return v;
}

// g_h += silu(layernorm(g_to + g_ho)) ; also refresh bf16 copy
__global__ __launch_bounds__(256) void k_combine(const float* __restrict__ g, const float* __restrict__ bt){
  int lane = threadIdx.x & 63;
  int node = blockIdx.x*4 + (threadIdx.x>>6);
  if (node>=NN) return;
  size_t i0 = (size_t)node*DD + lane, i1 = i0+64;
  float v0 = g_to[i0] + g_ho[i0];
  float v1 = g_to[i1] + g_ho[i1];
  float s = waveRed(v0+v1);
  float mean = s*(1.f/128.f);
  float d0=v0-mean, d1=v1-mean;
  float q = waveRed(d0*d0+d1*d1);
  float inv = 1.f/sqrtf(q*(1.f/128.f)+1e-5f);
  float c0 = d0*inv*g[lane]+bt[lane];
  float c1 = d1*inv*g[lane+64]+bt[lane+64];
  float h0 = g_h[i0] + c0/(1.f+expf(-c0));
  float h1 = g_h[i1] + c1/(1.f+expf(-c1));
  g_h[i0] = h0; g_h[i1] = h1;
  g_hb[i0] = f2bf(h0); g_hb[i1] = f2bf(h1);
}

// in-place final layernorm on g_h
__global__ __launch_bounds__(256) void k_finalln(const float* __restrict__ g, const float* __restrict__ b){
  int lane = threadIdx.x & 63;
  int node = blockIdx.x*4 + (threadIdx.x>>6);
  if (node>=NN) return;
  size_t i0 = (size_t)node*DD + lane, i1 = i0+64;
  float v0 = g_h[i0], v1 = g_h[i1];
  float s = waveRed(v0+v1);
  float mean = s*(1.f/128.f);
  float d0=v0-mean, d1=v1-mean;
  float q = waveRed(d0*d0+d1*d1);
  float inv = 1.f/sqrtf(q*(1.f/128.f)+1e-5f);
  g_h[i0]=d0*inv*g[lane]+b[lane];
  g_h[i1]=d1*inv*g[lane+64]+b[lane+64];
}

// mlp head: out3 = LN(silu(g_h@W1+b1)) @ W2 + b2 ; 8 nodes per block
__global__ __launch_bounds__(128) void k_head(
      const float* __restrict__ W1, const float* __restrict__ b1,
      const float* __restrict__ g, const float* __restrict__ bt,
      const float* __restrict__ W2, const float* __restrict__ b2,
      float* __restrict__ out){
  int d = threadIdx.x;
  int wv = d >> 6;
  int i0 = blockIdx.x*8;
  const int n = NN;
  __shared__ float rows[8][DD];
  __shared__ float comb[2];
#pragma unroll
  for (int t=0;t<8;++t){
    int node = i0+t;
    rows[t][d] = (node<n)? g_h[(size_t)node*DD+d] : 0.f;
  }
  __syncthreads();
  float z[8];
  float b1d = b1[d];
#pragma unroll
  for (int t=0;t<8;++t) z[t]=b1d;
  for (int k=0;k<DD;++k){
    float w = W1[k*DD+d];
#pragma unroll
    for (int t=0;t<8;++t) z[t] += rows[t][k]*w;
  }
#pragma unroll
  for (int t=0;t<8;++t){ float v=z[t]; z[t] = v/(1.f+expf(-v)); }
  float gd=g[d], btd=bt[d];
  float w2a=W2[d*3+0], w2b=W2[d*3+1], w2c=W2[d*3+2];
  float b2a=b2[0], b2b=b2[1], b2c=b2[2];
  for (int t=0;t<8;++t){
    int node=i0+t;
    float zz=z[t];
    float s = waveRed(zz);
    if ((d&63)==0) comb[wv]=s;
    __syncthreads();
    float mean=(comb[0]+comb[1])*(1.f/128.f);
    __syncthreads();
    float dv=zz-mean;
    float q2 = waveRed(dv*dv);
    if ((d&63)==0) comb[wv]=q2;
    __syncthreads();
    float inv = 1.f/sqrtf((comb[0]+comb[1])*(1.f/128.f)+1e-5f);
    __syncthreads();
    float zn = dv*inv*gd+btd;
    float p0 = waveRed(zn*w2a);
    if ((d&63)==0) comb[wv]=p0;
    __syncthreads();
    float o0 = comb[0]+comb[1]+b2a;
    __syncthreads();
    float p1 = waveRed(zn*w2b);
    if ((d&63)==0) comb[wv]=p1;
    __syncthreads();
    float o1 = comb[0]+comb[1]+b2b;
    __syncthreads();
    float p2 = waveRed(zn*w2c);
    if ((d&63)==0) comb[wv]=p2;
    __syncthreads();
    float o2 = comb[0]+comb[1]+b2c;
    __syncthreads();
    if (d==0 && node<n){
      out[(size_t)node*3+0]=o0; out[(size_t)node*3+1]=o1; out[(size_t)node*3+2]=o2;
    }
  }
}

extern "C" void kernel_launch(void* const* d_in, const int* in_sizes, int n_in,
                              void* d_out, int out_size, void* d_ws, size_t ws_size,
                              hipStream_t stream){
  (void)in_sizes; (void)n_in; (void)out_size; (void)d_ws; (void)ws_size;
  const float* x    = (const float*)d_in[0];
  const int*   eit  = (const int*)d_in[1];
  const int*   eih  = (const int*)d_in[2];
  const float* eat  = (const float*)d_in[3];
  const float* eah  = (const float*)d_in[4];
  const float* W_te = (const float*)d_in[5];
  const float* b_te = (const float*)d_in[6];
  const float* W_he = (const float*)d_in[7];
  const float* b_he = (const float*)d_in[8];
  const float *Wq_t=(const float*)d_in[9],  *bq_t=(const float*)d_in[10];
  const float *Wk_t=(const float*)d_in[11], *bk_t=(const float*)d_in[12];
  const float *Wv_t=(const float*)d_in[13], *bv_t=(const float*)d_in[14];
  const float *We_t=(const float*)d_in[15];
  const float *Ws_t=(const float*)d_in[16], *bs_t=(const float*)d_in[17];
  const float *Wq_h=(const float*)d_in[18], *bq_h=(const float*)d_in[19];
  const float *Wk_h=(const float*)d_in[20], *bk_h=(const float*)d_in[21];
  const float *Wv_h=(const float*)d_in[22], *bv_h=(const float*)d_in[23];
  const float *We_h=(const float*)d_in[24];
  const float *Ws_h=(const float*)d_in[25], *bs_h=(const float*)d_in[26];
  const float *norm_g=(const float*)d_in[27], *norm_b=(const float*)d_in[28];
  const float *fg=(const float*)d_in[29], *fb=(const float*)d_in[30];
  const float *dW1=(const float*)d_in[31], *db1=(const float*)d_in[32];
  const float *dg=(const float*)d_in[33],  *dbt=(const float*)d_in[34];
  const float *dW2=(const float*)d_in[35], *db2=(const float*)d_in[36];
  const float *sW1=(const float*)d_in[37], *sb1=(const float*)d_in[38];
  const float *sg=(const float*)d_in[39],  *sbt=(const float*)d_in[40];
  const float *sW2=(const float*)d_in[41], *sb2=(const float*)d_in[42];
  float* outp = (float*)d_out;

  k_copy_h<<<cdiv(NN*DD/4,256),256,0,stream>>>(x);

  WPtrs wp;
  for (int l=0;l<NL;++l){
    wp.W[l*8+0]=Wq_t+(size_t)l*DD*DD; wp.W[l*8+1]=Wk_t+(size_t)l*DD*DD;
    wp.W[l*8+2]=Wv_t+(size_t)l*DD*DD; wp.W[l*8+3]=Ws_t+(size_t)l*DD*DD;
    wp.W[l*8+4]=Wq_h+(size_t)l*DD*DD; wp.W[l*8+5]=Wk_h+(size_t)l*DD*DD;
    wp.W[l*8+6]=Wv_h+(size_t)l*DD*DD; wp.W[l*8+7]=Ws_h+(size_t)l*DD*DD;
  }
  k_cvtw<<<dim3(64,24),256,0,stream>>>(wp);

  k_zero_cnt<<<dim3(cdiv(NN,256),2),256,0,stream>>>();
  k_hist<<<dim3(cdiv(ET_N,256),2),256,0,stream>>>(eit+ET_N, eih+EH_N);
  k_scan<<<dim3(1,2),1024,0,stream>>>();
  k_scatter<<<dim3(cdiv(ET_N,256),2),256,0,stream>>>(eit, eih, eat, eah, W_te, b_te, W_he, b_he);

  for (int l=0;l<NL;++l){
    BiasP bp;
    bp.b[0]=bq_t+(size_t)l*DD; bp.b[1]=bk_t+(size_t)l*DD;
    bp.b[2]=bv_t+(size_t)l*DD; bp.b[3]=bs_t+(size_t)l*DD;
    bp.b[4]=bq_h+(size_t)l*DD; bp.b[5]=bk_h+(size_t)l*DD;
    bp.b[6]=bv_h+(size_t)l*DD; bp.b[7]=bs_h+(size_t)l*DD;
    k_gemm_mfma<<<dim3(cdiv(NN,64),6),256,0,stream>>>(l, bp);
    k_agg<<<dim3(NN,2),128,0,stream>>>(We_t+(size_t)l*4*DD, We_h+(size_t)l*4*DD);
    k_combine<<<cdiv(NN,4),256,0,stream>>>(norm_g+(size_t)l*DD, norm_b+(size_t)l*DD);
  }
  k_finalln<<<cdiv(NN,4),256,0,stream>>>(fg, fb);
  k_head<<<cdiv(NN,8),128,0,stream>>>(dW1, db1, dg, dbt, dW2, db2, outp);
  k_head<<<cdiv(NN,8),128,0,stream>>>(sW1, sb1, sg, sbt, sW2, sb2, outp+(size_t)NN*3);
}